// Round 1
// 296.837 us; speedup vs baseline: 1.0189x; 1.0189x over previous
//
#include <hip/hip_runtime.h>
#include <hip/hip_fp16.h>
#include <cstdint>
#include <cstddef>

#define QL 16
#define LSH 8192
#define LWK 2048
#define SCALE 0.08838834764831845f  // 1/sqrt(128)

typedef __attribute__((ext_vector_type(8))) short short8;
typedef __attribute__((ext_vector_type(4))) short short4v;
typedef __attribute__((ext_vector_type(4))) float f32x4;
typedef __attribute__((ext_vector_type(8))) unsigned short ushort8v;

#if defined(__has_builtin)
#if __has_builtin(__builtin_amdgcn_mfma_f32_16x16x16bf16_1k)
#define HAVE_MFMA16 1
#endif
#endif

__device__ __forceinline__ unsigned short f2bf(float f) {
  unsigned int u = __float_as_uint(f);
  u += 0x7fffu + ((u >> 16) & 1u);
  return (unsigned short)(u >> 16);
}
__device__ __forceinline__ float bf2f(unsigned short b) {
  return __uint_as_float(((unsigned int)b) << 16);
}

// async global->LDS, 16 B per lane; lds base must be wave-uniform.
__device__ __forceinline__ void gload_lds16(const float* g, float* lds) {
  __builtin_amdgcn_global_load_lds(
      (const __attribute__((address_space(1))) void*)g,
      (__attribute__((address_space(3))) void*)lds, 16, 0, 0);
}

// ---------------------------------------------------------------------------
// Cast fp32 -> bf16 (hidden_states). n4 float4 groups.
// ---------------------------------------------------------------------------
__global__ __launch_bounds__(256) void k_cast(
    const float* __restrict__ in, unsigned short* __restrict__ outp, int n4)
{
  int i = blockIdx.x * 256 + threadIdx.x;
  if (i < n4) {
    float4 v = ((const float4*)in)[i];
    ushort4 p; p.x = f2bf(v.x); p.y = f2bf(v.y); p.z = f2bf(v.z); p.w = f2bf(v.w);
    ((ushort4*)outp)[i] = p;
  }
}

// ---------------------------------------------------------------------------
// out[32 x Ntot] = Xbf @ Wcat^T. m97-style: W fp32 staged via global_load_lds
// (coalesced 1KB/instr, zero staging VGPRs), bf16 convert at frag-read.
// Split-K x2: blockIdx.x = colblock*2 + khalf; khalf k-range 2048, 4 chunks
// of 512. Partials to outA / outB (summed downstream).
// LDS rows padded +16B (stride 516 floats): bank phase 4 -> ~conflict-free.
// ---------------------------------------------------------------------------
__global__ __launch_bounds__(256) void k_gemm4(
    const unsigned short* __restrict__ Xbf,
    const float* __restrict__ W0, const float* __restrict__ W1, const float* __restrict__ W2,
    const float* __restrict__ b0, const float* __restrict__ b1, const float* __restrict__ b2,
    float* __restrict__ outA, float* __restrict__ outB, int Ntot)
{
  __shared__ float Ws[16 * 516];   // 33 KB; reused as Red in epilogue
  const int bx = blockIdx.x;
  const int n0 = (bx >> 1) * 16;
  const int khalf = bx & 1;
  const float* W; const float* bias; int row0;
  if (n0 < 4096)      { W = W0; bias = b0; row0 = n0; }
  else if (n0 < 5120) { W = W1; bias = b1; row0 = n0 - 4096; }
  else                { W = W2; bias = b2; row0 = n0 - 5120; }
  const int t = threadIdx.x;
  const int w_id = t >> 6;
  const int lane = t & 63;
  const int l15 = lane & 15;
  const int quad = lane >> 4;
  const int cb0 = khalf * 2048;

  f32x4 C0 = {0.f,0.f,0.f,0.f}, C1 = {0.f,0.f,0.f,0.f};

  for (int c = 0; c < 4; ++c) {
    const int cbase = cb0 + c * 512;
    __syncthreads();                       // LDS free (prev chunk consumed)
#pragma unroll
    for (int i = 0; i < 8; ++i) {          // 32 instrs: 16 rows x 2 halves
      int idx = w_id * 8 + i;
      int r = idx >> 1, hh = idx & 1;
      const float* g = W + (size_t)(row0 + r) * 4096 + cbase + hh * 256 + lane * 4;
      gload_lds16(g, &Ws[r * 516 + hh * 256]);
    }
    __syncthreads();                       // vmcnt drain -> LDS valid
    const int wk = w_id * 128;             // wave k-slice within chunk
#pragma unroll
    for (int ks = 0; ks < 4; ++ks) {
      int ko = wk + ks * 32 + quad * 8;
      f32x4 wlo = *(const f32x4*)(&Ws[l15 * 516 + ko]);
      f32x4 whi = *(const f32x4*)(&Ws[l15 * 516 + ko + 4]);
      short8 bfr;
      bfr[0] = (short)f2bf(wlo[0]); bfr[1] = (short)f2bf(wlo[1]);
      bfr[2] = (short)f2bf(wlo[2]); bfr[3] = (short)f2bf(wlo[3]);
      bfr[4] = (short)f2bf(whi[0]); bfr[5] = (short)f2bf(whi[1]);
      bfr[6] = (short)f2bf(whi[2]); bfr[7] = (short)f2bf(whi[3]);
      short8 a0 = *(const short8*)(Xbf + (size_t)l15 * 4096 + cbase + ko);
      short8 a1 = *(const short8*)(Xbf + (size_t)(16 + l15) * 4096 + cbase + ko);
      C0 = __builtin_amdgcn_mfma_f32_16x16x32_bf16(a0, bfr, C0, 0, 0, 0);
      C1 = __builtin_amdgcn_mfma_f32_16x16x32_bf16(a1, bfr, C1, 0, 0, 0);
    }
  }
  __syncthreads();
  float* Red = Ws;
#pragma unroll
  for (int i = 0; i < 4; ++i) {
    Red[w_id * 512 + (quad * 4 + i) * 16 + l15] = C0[i];
    Red[w_id * 512 + 256 + (quad * 4 + i) * 16 + l15] = C1[i];
  }
  __syncthreads();
  float* dst = khalf ? outB : outA;
#pragma unroll
  for (int e = t; e < 512; e += 256) {
    float s = Red[e] + Red[512 + e] + Red[1024 + e] + Red[1536 + e];
    int m = e >> 4, n = e & 15;
    if (khalf == 0 && bias) s += bias[row0 + n];
    dst[(size_t)m * Ntot + n0 + n] = s;
  }
}

// ---------------------------------------------------------------------------
// out = A + B (float4 groups), for split-K combine of the output projection.
// ---------------------------------------------------------------------------
__global__ __launch_bounds__(256) void k_add(
    const float* __restrict__ A, const float* __restrict__ B,
    float* __restrict__ o, int n4)
{
  int i = blockIdx.x * 256 + threadIdx.x;
  if (i < n4) {
    float4 a = ((const float4*)A)[i], b = ((const float4*)B)[i];
    float4 r; r.x = a.x + b.x; r.y = a.y + b.y; r.z = a.z + b.z; r.w = a.w + b.w;
    ((float4*)o)[i] = r;
  }
}

// ---------------------------------------------------------------------------
// RoPE: rq (3 variants: pos 12304+q / 4112+q / 2048+q, scale folded),
// RoPE'd k_new and v_new, all bf16. qkv = qkvA + qkvB (split-K halves).
// ---------------------------------------------------------------------------
__global__ __launch_bounds__(256) void k_rope(
    const float* __restrict__ qA, const float* __restrict__ qB,
    const float* __restrict__ cosn, const float* __restrict__ sinn,
    unsigned short* __restrict__ rq, unsigned short* __restrict__ knew,
    unsigned short* __restrict__ vnew)
{
  const int g = blockIdx.x * 256 + threadIdx.x;
  const float LOGTH = 9.210340371976184f; // ln(10000)
  if (g < 393216) {                          // rq: [var][w][head][q][d]
    int d = g & 127, q = (g >> 7) & 15, head = (g >> 11) & 31, w = (g >> 16) & 1, var = g >> 17;
    int tok = w * 16 + q;
    int col = head * 128 + d;
    size_t ix = (size_t)tok * 6144 + col;
    float val = qA[ix] + qB[ix];
    size_t ir = (d < 64) ? ix + 64 : ix - 64;
    float rot = qA[ir] + qB[ir];
    if (d < 64) rot = -rot;
    int pos = (var == 0 ? 12304 : (var == 1 ? 4112 : 2048)) + q;
    int i = d & 63;
    float inv = expf(-(float)i * (LOGTH / 64.0f));
    float ang = (float)pos * inv;
    float c = cosf(ang), s = sinf(ang);
    rq[g] = f2bf((val * c + rot * s) * SCALE);
  } else {
    int g2 = g - 393216;
    if (g2 < 65536) {
      int isv = (g2 >= 32768);
      if (isv) g2 -= 32768;
      int d = g2 & 127, q = (g2 >> 7) & 15, h = (g2 >> 11) & 7, w = (g2 >> 14) & 1;
      int tok = w * 16 + q;
      if (isv) {
        size_t ix = (size_t)tok * 6144 + 5120 + h * 128 + d;
        vnew[g2] = f2bf(qA[ix] + qB[ix]);
      } else {
        size_t ix = (size_t)tok * 6144 + 4096 + h * 128 + d;
        float val = qA[ix] + qB[ix];
        size_t ir = (d < 64) ? ix + 64 : ix - 64;
        float rot = qA[ir] + qB[ir];
        if (d < 64) rot = -rot;
        float c = cosn[tok * 128 + d], s = sinn[tok * 128 + d];
        knew[g2] = f2bf(val * c + rot * s);
      }
    }
  }
}

// ---------------------------------------------------------------------------
// Flash-attention partials, fixed-max softmax, SWAPPED QK operands:
// S' = C[m=key][n=q] (col=lane&15 = q, row = quad*4+i = key). P then exits
// in exactly the 16x16x16 MFMA A-layout (m=q in l15, k=key in quad*4+j), so
// PV needs no LDS round-trip. exp via __expf. l-reduction = 2 shfl steps.
//
// R1 restructure: 8 waves x 512 threads, ONE q-head per wave (the old mt
// loop is now the wave index). Per-thread register demand drops from ~176
// (which forced the compiler to sink the prefetch loads -> exposed HBM
// latency every tile, 15k cy/tile, 11.6% occupancy, all pipes idle) to
// ~120: acc[8]=32 + arq[4]=16 + staging kf[4]+vf[16]=32 + temps. With
// launch_bounds(512,2) the allocator has slack, so the 20 staging loads
// stay hoisted and in flight across the whole compute phase.
// accP/lP row layout (worker*64 + hq*16 + q) is IDENTICAL to the old
// (w_id*32 + mt*16 + q) mapping, so k_combine is unchanged.
// ---------------------------------------------------------------------------
__global__ __launch_bounds__(512, 2) void k_attn(
    const float* __restrict__ shk, const float* __restrict__ shv,
    const float* __restrict__ w0k, const float* __restrict__ w0v,
    const float* __restrict__ w1k, const float* __restrict__ w1v,
    const unsigned short* __restrict__ rq,
    const unsigned short* __restrict__ knew, const unsigned short* __restrict__ vnew,
    __half* __restrict__ accP, float* __restrict__ lP)
{
  __shared__ alignas(16) unsigned short Ks[64 * 136];    // [key][d] bf16
  __shared__ alignas(16) unsigned short Vts[128 * 72];   // [d][key] bf16
#ifndef HAVE_MFMA16
  __shared__ alignas(16) unsigned short Plds[8 * 16 * 72];
#endif

  const int h = blockIdx.x / 50;
  const int cidx = blockIdx.x % 50;
  int kind, k0, nk; bool is_new;
  if (cidx < 32)      { kind = 0; k0 = cidx * 256; nk = 256; is_new = false; }
  else if (cidx < 41) { int c = cidx - 32; kind = 1; k0 = c * 256; nk = (c == 8) ? 16 : 256; is_new = (c == 8); }
  else                { int c = cidx - 41; kind = 2; k0 = c * 256; nk = (c == 8) ? 16 : 256; is_new = (c == 8); }

  const int t = threadIdx.x;
  const int w_id = t >> 6;        // 0..7
  const int lane = t & 63;
  const int l15 = lane & 15;
  const int quad = lane >> 4;
  const int worker = w_id >> 2;   // 0..1
  const int hq = w_id & 3;        // q-head within kv group
  // staging decompositions (512 threads)
  const int col4 = t & 31;        // K: float4 column within row
  const int rowb = t >> 5;        // K: base row 0..15
  const int dv = t & 127;         // V: d column
  const int tg = t >> 7;          // V: key-row group 0..3

  int var; bool causal;
  if (kind == 0)      { var = 0; causal = false; }
  else if (kind == 1) { var = (worker == 0) ? 2 : 1; causal = (worker == 0); }
  else                { var = (worker == 1) ? 2 : 1; causal = (worker == 1); }

  const float* Ksrc = (kind == 0) ? (shk + (size_t)h * LSH * 128)
                     : (kind == 1) ? (w0k + (size_t)h * LWK * 128)
                                   : (w1k + (size_t)h * LWK * 128);
  const float* Vsrc = (kind == 0) ? (shv + (size_t)h * LSH * 128)
                     : (kind == 1) ? (w0v + (size_t)h * LWK * 128)
                                   : (w1v + (size_t)h * LWK * 128);
  const int wseg = (kind == 2) ? 1 : 0;
  const unsigned short* knsrc = knew + ((size_t)wseg * 8 + h) * 16 * 128;
  const unsigned short* vnsrc = vnew + ((size_t)wseg * 8 + h) * 16 * 128;

  // B-fragment of rq for this wave's head (B[n=q][k=d])
  const int head = h * 4 + hq;
  short8 arq[4];
  {
    const unsigned short* base =
        rq + ((((size_t)var * 2 + worker) * 32 + head) * 16 + l15) * 128 + quad * 8;
#pragma unroll
    for (int ks = 0; ks < 4; ++ks) arq[ks] = *(const short8*)(base + ks * 32);
  }

  float lrow = 0.f;
  f32x4 acc[8];
#pragma unroll
  for (int dt = 0; dt < 8; ++dt) acc[dt] = {0.f,0.f,0.f,0.f};

  // raw fp32 staging registers — branch-free bulk loads, 32 VGPRs total
  float4 kf[4];
  float  vf[16];

  auto load_tile = [&](int st) {
    const int kb = k0 + st * 64;
    if (!is_new) {
#pragma unroll
      for (int i = 0; i < 4; ++i)
        kf[i] = *(const float4*)(Ksrc + (size_t)(kb + i * 16 + rowb) * 128 + col4 * 4);
#pragma unroll
      for (int g = 0; g < 2; ++g)
#pragma unroll
        for (int i = 0; i < 8; ++i)
          vf[g * 8 + i] = Vsrc[(size_t)(kb + g * 32 + tg * 8 + i) * 128 + dv];
    } else {
      // 16 new tokens, bf16 source. Clamp rows (&15); garbage rows are
      // killed by the score mask (P = 0), so V garbage is harmless.
#pragma unroll
      for (int i = 0; i < 4; ++i) {
        ushort4 p = *(const ushort4*)(knsrc + (size_t)((i * 16 + rowb) & 15) * 128 + col4 * 4);
        kf[i].x = bf2f(p.x); kf[i].y = bf2f(p.y);
        kf[i].z = bf2f(p.z); kf[i].w = bf2f(p.w);
      }
#pragma unroll
      for (int g = 0; g < 2; ++g)
#pragma unroll
        for (int i = 0; i < 8; ++i)
          vf[g * 8 + i] = bf2f(vnsrc[(size_t)((g * 32 + tg * 8 + i) & 15) * 128 + dv]);
    }
  };

  const int nst = (nk + 63) >> 6;
  load_tile(0);

  for (int st = 0; st < nst; ++st) {
    __syncthreads();
    // ---- convert + regs -> LDS (single vmcnt drain here) ----
#pragma unroll
    for (int i = 0; i < 4; ++i) {
      ushort4 p; p.x = f2bf(kf[i].x); p.y = f2bf(kf[i].y);
      p.z = f2bf(kf[i].z); p.w = f2bf(kf[i].w);
      *(ushort4*)(&Ks[(i * 16 + rowb) * 136 + col4 * 4]) = p;
    }
#pragma unroll
    for (int g = 0; g < 2; ++g) {
      ushort8v p;
#pragma unroll
      for (int i = 0; i < 8; ++i) p[i] = f2bf(vf[g * 8 + i]);
      *(ushort8v*)(&Vts[dv * 72 + (g * 4 + tg) * 8]) = p;
    }
    __syncthreads();
    if (st + 1 < nst) load_tile(st + 1);  // 20 loads in flight across compute

    // ---- S' = K x Q^T : A = K-frag (m=key), B = rq (n=q) ----
    f32x4 S[4];
#pragma unroll
    for (int nt = 0; nt < 4; ++nt) S[nt] = {0.f,0.f,0.f,0.f};
#pragma unroll
    for (int ks = 0; ks < 4; ++ks)
#pragma unroll
      for (int nt = 0; nt < 4; ++nt) {
        short8 kfr = *(const short8*)(&Ks[(nt * 16 + l15) * 136 + ks * 32 + quad * 8]);
        S[nt] = __builtin_amdgcn_mfma_f32_16x16x32_bf16(kfr, arq[ks], S[nt], 0, 0, 0);
      }
    if (is_new) {
#pragma unroll
      for (int nt = 0; nt < 4; ++nt)
#pragma unroll
        for (int i = 0; i < 4; ++i) {
          int loc = st * 64 + nt * 16 + quad * 4 + i;   // key index
          if (loc >= nk || (causal && loc > l15)) S[nt][i] = -3.0e38f;
        }
    }
    float rs = 0.0f;
#pragma unroll
    for (int nt = 0; nt < 4; ++nt)
#pragma unroll
      for (int i = 0; i < 4; ++i) {
        float p = __expf(fminf(S[nt][i], 60.0f));
        S[nt][i] = p;
        rs += p;
      }
#ifdef HAVE_MFMA16
    short4v pv[4];
#pragma unroll
    for (int nt = 0; nt < 4; ++nt) {
      short4v pp;
      pp[0] = (short)f2bf(S[nt][0]); pp[1] = (short)f2bf(S[nt][1]);
      pp[2] = (short)f2bf(S[nt][2]); pp[3] = (short)f2bf(S[nt][3]);
      pv[nt] = pp;
    }
#else
#pragma unroll
    for (int nt = 0; nt < 4; ++nt)
#pragma unroll
      for (int i = 0; i < 4; ++i)
        Plds[w_id * (16 * 72) + l15 * 72 + nt * 16 + quad * 4 + i] = f2bf(S[nt][i]);
#endif
    // denominator: sum across quads (keys); q = l15 fixed per lane
    rs += __shfl_xor(rs, 16, 64);
    rs += __shfl_xor(rs, 32, 64);
    lrow += rs;

    // ---- PV ----
#ifdef HAVE_MFMA16
#pragma unroll
    for (int dt = 0; dt < 8; ++dt)
#pragma unroll
      for (int kc = 0; kc < 4; ++kc) {
        short4v vfr = *(const short4v*)(&Vts[(dt * 16 + l15) * 72 + kc * 16 + quad * 4]);
        acc[dt] = __builtin_amdgcn_mfma_f32_16x16x16bf16_1k(pv[kc], vfr, acc[dt], 0, 0, 0);
      }
#else
    short8 ap[2];
#pragma unroll
    for (int ks2 = 0; ks2 < 2; ++ks2)
      ap[ks2] = *(const short8*)(
          &Plds[w_id * (16 * 72) + l15 * 72 + ks2 * 32 + quad * 8]);
#pragma unroll
    for (int dt = 0; dt < 8; ++dt)
#pragma unroll
      for (int ks2 = 0; ks2 < 2; ++ks2) {
        short8 vfr = *(const short8*)(&Vts[(dt * 16 + l15) * 72 + ks2 * 32 + quad * 8]);
        acc[dt] = __builtin_amdgcn_mfma_f32_16x16x32_bf16(ap[ks2], vfr, acc[dt], 0, 0, 0);
      }
#endif
  }

  // ---- write partials (acc layout: row = q = quad*4+i, col = d = dt*16+l15)
  __half* accB = accP + (size_t)blockIdx.x * 128 * 128;
  const int wrow = worker * 64 + hq * 16;
#pragma unroll
  for (int dt = 0; dt < 8; ++dt)
#pragma unroll
    for (int i = 0; i < 4; ++i) {
      int row = wrow + quad * 4 + i;
      int d = dt * 16 + l15;
      accB[row * 128 + d] = __float2half(acc[dt][i]);
    }
  if (quad == 0) {
    int row = wrow + l15;    // q = l15
    lP[(size_t)blockIdx.x * 128 + row] = lrow;
  }
}

// ---------------------------------------------------------------------------
// Combine 50 chunk-partials per (head,row): plain sums (fixed-max softmax).
// ---------------------------------------------------------------------------
__global__ __launch_bounds__(128) void k_combine(
    const __half* __restrict__ accP, const float* __restrict__ lP,
    unsigned short* __restrict__ attnX)
{
  __shared__ float sl[50];
  const int h = blockIdx.x >> 7;
  const int r = blockIdx.x & 127;
  const int d = threadIdx.x;
  if (d < 50) sl[d] = lP[(size_t)(h * 50 + d) * 128 + r];
  __syncthreads();
  float L = 0.0f, A = 0.0f;
#pragma unroll
  for (int c = 0; c < 50; ++c) L += sl[c];
#pragma unroll
  for (int cc = 0; cc < 50; cc += 10) {
    float p[10];
#pragma unroll
    for (int i = 0; i < 10; ++i)
      p[i] = __half2float(accP[((size_t)(h * 50 + cc + i) * 128 + r) * 128 + d]);
#pragma unroll
    for (int i = 0; i < 10; ++i) A += p[i];
  }
  int workerv = r >> 6, headpairv = (r >> 5) & 1, mtv = (r >> 4) & 1, q = r & 15;
  int head = h * 4 + headpairv * 2 + mtv;
  attnX[(size_t)(workerv * 16 + q) * 4096 + head * 128 + d] = f2bf(A / L);
}

// ---------------------------------------------------------------------------
extern "C" void kernel_launch(void* const* d_in, const int* in_sizes, int n_in,
                              void* d_out, int out_size, void* d_ws, size_t ws_size,
                              hipStream_t stream)
{
  const float* hs   = (const float*)d_in[0];
  const float* Wq   = (const float*)d_in[1];
  const float* bq   = (const float*)d_in[2];
  const float* Wk   = (const float*)d_in[3];
  const float* bk   = (const float*)d_in[4];
  const float* Wv   = (const float*)d_in[5];
  const float* bv   = (const float*)d_in[6];
  const float* Wo   = (const float*)d_in[7];
  const float* shk  = (const float*)d_in[8];
  const float* shv  = (const float*)d_in[9];
  const float* w0k  = (const float*)d_in[10];
  const float* w0v  = (const float*)d_in[11];
  const float* w1k  = (const float*)d_in[12];
  const float* w1v  = (const float*)d_in[13];
  const float* cosn = (const float*)d_in[14];
  const float* sinn = (const float*)d_in[15];
  float* out = (float*)d_out;

  char* ws = (char*)d_ws;
  float*          qkvA   = (float*)(ws + 0);                //  32*6144 f32
  unsigned short* rq     = (unsigned short*)(ws + 786432);  //  3*2*32*16*128 bf16
  unsigned short* knew   = (unsigned short*)(ws + 1572864); //  2*8*16*128 bf16
  unsigned short* vnew   = (unsigned short*)(ws + 1638400);
  unsigned short* hsbf   = (unsigned short*)(ws + 1703936); //  32*4096 bf16
  unsigned short* attnXb = (unsigned short*)(ws + 1966080); //  32*4096 bf16
  float*          lP     = (float*)(ws + 2228224);          //  400*128 f32
  __half*         accP   = (__half*)(ws + 2433024);         //  400*128*128 f16 (13.1 MB)
  float*          qkvB   = (float*)(ws + 15540224);         //  32*6144 f32
  // out-proj split-K halves live inside accP's region (accP consumed by then)
  float*          outA   = (float*)(ws + 2433024);
  float*          outB   = (float*)(ws + 2433024 + 786432);

  // 1. cast hidden_states to bf16
  k_cast<<<128, 256, 0, stream>>>(hs, hsbf, 32768);
  // 2. QKV projection, split-K x2 (bias in khalf==0 partial)
  k_gemm4<<<768, 256, 0, stream>>>(hsbf, Wq, Wk, Wv, bq, bk, bv, qkvA, qkvB, 6144);
  // 3. RoPE (q x 3 variants + k_new) + v_new, bf16 (sums qkvA+qkvB)
  k_rope<<<1792, 256, 0, stream>>>(qkvA, qkvB, cosn, sinn, rq, knew, vnew);
  // 4. flash-attention partials over 8 heads x 50 key-chunks (8 waves/block)
  k_attn<<<400, 512, 0, stream>>>(shk, shv, w0k, w0v, w1k, w1v, rq, knew, vnew, accP, lP);
  // 5. combine partials -> attnX (bf16)
  k_combine<<<1024, 128, 0, stream>>>(accP, lP, attnXb);
  // 6. output projection, split-K x2
  k_gemm4<<<512, 256, 0, stream>>>(attnXb, Wo, Wo, Wo, nullptr, nullptr, nullptr, outA, outB, 4096);
  // 7. sum halves -> d_out
  k_add<<<192, 256, 0, stream>>>(outA, outB, out, 49152);
}

// Round 2
// 295.362 us; speedup vs baseline: 1.0240x; 1.0050x over previous
//
#include <hip/hip_runtime.h>
#include <hip/hip_fp16.h>
#include <cstdint>
#include <cstddef>

#define QL 16
#define LSH 8192
#define LWK 2048
#define SCALE 0.08838834764831845f  // 1/sqrt(128)

typedef __attribute__((ext_vector_type(8))) short short8;
typedef __attribute__((ext_vector_type(4))) short short4v;
typedef __attribute__((ext_vector_type(4))) float f32x4;
typedef __attribute__((ext_vector_type(8))) unsigned short ushort8v;

#if defined(__has_builtin)
#if __has_builtin(__builtin_amdgcn_mfma_f32_16x16x16bf16_1k)
#define HAVE_MFMA16 1
#endif
#endif

__device__ __forceinline__ unsigned short f2bf(float f) {
  unsigned int u = __float_as_uint(f);
  u += 0x7fffu + ((u >> 16) & 1u);
  return (unsigned short)(u >> 16);
}
__device__ __forceinline__ float bf2f(unsigned short b) {
  return __uint_as_float(((unsigned int)b) << 16);
}

// async global->LDS, 16 B per lane; lds base must be wave-uniform.
__device__ __forceinline__ void gload_lds16(const float* g, float* lds) {
  __builtin_amdgcn_global_load_lds(
      (const __attribute__((address_space(1))) void*)g,
      (__attribute__((address_space(3))) void*)lds, 16, 0, 0);
}

// --- inline-asm global loads: compiler can neither sink them past compute
// --- nor auto-drain them at barriers (we do counted/placed waits manually).
__device__ __forceinline__ void gload_f4(float4& d, const float* p) {
  asm volatile("global_load_dwordx4 %0, %1, off"
               : "=v"(d)
               : "v"((const __attribute__((address_space(1))) float*)p));
}
__device__ __forceinline__ void gload_f1(float& d, const float* p) {
  asm volatile("global_load_dword %0, %1, off"
               : "=v"(d)
               : "v"((const __attribute__((address_space(1))) float*)p));
}
__device__ __forceinline__ void gload_s8(short8& d, const unsigned short* p) {
  asm volatile("global_load_dwordx4 %0, %1, off"
               : "=v"(d)
               : "v"((const __attribute__((address_space(1))) unsigned short*)p));
}

// ---------------------------------------------------------------------------
// Cast fp32 -> bf16 (hidden_states). n4 float4 groups.
// ---------------------------------------------------------------------------
__global__ __launch_bounds__(256) void k_cast(
    const float* __restrict__ in, unsigned short* __restrict__ outp, int n4)
{
  int i = blockIdx.x * 256 + threadIdx.x;
  if (i < n4) {
    float4 v = ((const float4*)in)[i];
    ushort4 p; p.x = f2bf(v.x); p.y = f2bf(v.y); p.z = f2bf(v.z); p.w = f2bf(v.w);
    ((ushort4*)outp)[i] = p;
  }
}

// ---------------------------------------------------------------------------
// out[32 x Ntot] = Xbf @ Wcat^T.
// R2: T3/T4 pipeline. Double-buffered Ws (66KB). Per chunk c:
//   issue xa(c) A-frag asm loads -> issue stage(c+1) gload_lds -> vmcnt(8)
//   (keeps c+1 in flight; vmcnt retires in order so xa(c)+stage(c) are done)
//   -> raw s_barrier -> MFMA -> raw s_barrier.  NO vmcnt(0) until last chunk.
// ---------------------------------------------------------------------------
__global__ __launch_bounds__(256) void k_gemm4(
    const unsigned short* __restrict__ Xbf,
    const float* __restrict__ W0, const float* __restrict__ W1, const float* __restrict__ W2,
    const float* __restrict__ b0, const float* __restrict__ b1, const float* __restrict__ b2,
    float* __restrict__ outA, float* __restrict__ outB, int Ntot)
{
  __shared__ float Ws[2][16 * 516];   // 2 x 33 KB double buffer; Red reuses buf0
  const int bx = blockIdx.x;
  const int n0 = (bx >> 1) * 16;
  const int khalf = bx & 1;
  const float* W; const float* bias; int row0;
  if (n0 < 4096)      { W = W0; bias = b0; row0 = n0; }
  else if (n0 < 5120) { W = W1; bias = b1; row0 = n0 - 4096; }
  else                { W = W2; bias = b2; row0 = n0 - 5120; }
  const int t = threadIdx.x;
  const int w_id = t >> 6;
  const int lane = t & 63;
  const int l15 = lane & 15;
  const int quad = lane >> 4;
  const int cb0 = khalf * 2048;
  const int wk = w_id * 128;

  f32x4 C0 = {0.f,0.f,0.f,0.f}, C1 = {0.f,0.f,0.f,0.f};
  short8 xa0[4], xa1[4];

  auto stage = [&](int c, int b) {
    const int cbase = cb0 + c * 512;
#pragma unroll
    for (int i = 0; i < 8; ++i) {          // 8 instrs/wave: 16 rows x 2 halves
      int idx = w_id * 8 + i;
      int r = idx >> 1, hh = idx & 1;
      const float* g = W + (size_t)(row0 + r) * 4096 + cbase + hh * 256 + lane * 4;
      gload_lds16(g, &Ws[b][r * 516 + hh * 256]);
    }
  };

  stage(0, 0);
#pragma unroll
  for (int c = 0; c < 4; ++c) {
    const int cbase = cb0 + c * 512;
    // A-fragments for chunk c (asm; issued BEFORE stage(c+1) so vmcnt(8)
    // retires them together with stage(c) while stage(c+1) stays in flight)
#pragma unroll
    for (int ks = 0; ks < 4; ++ks) {
      int ko = wk + ks * 32 + quad * 8;
      gload_s8(xa0[ks], Xbf + (size_t)l15 * 4096 + cbase + ko);
      gload_s8(xa1[ks], Xbf + (size_t)(16 + l15) * 4096 + cbase + ko);
    }
    __builtin_amdgcn_sched_barrier(0);
    if (c < 3) {
      stage(c + 1, (c + 1) & 1);
      asm volatile("s_waitcnt vmcnt(8)" ::: "memory");
    } else {
      asm volatile("s_waitcnt vmcnt(0)" ::: "memory");
    }
    __builtin_amdgcn_sched_barrier(0);
    __builtin_amdgcn_s_barrier();          // all waves' chunk-c staging done
    __builtin_amdgcn_sched_barrier(0);
    const float* Wsb = Ws[c & 1];
#pragma unroll
    for (int ks = 0; ks < 4; ++ks) {
      int ko = wk + ks * 32 + quad * 8;
      f32x4 wlo = *(const f32x4*)(&Wsb[l15 * 516 + ko]);
      f32x4 whi = *(const f32x4*)(&Wsb[l15 * 516 + ko + 4]);
      short8 bfr;
      bfr[0] = (short)f2bf(wlo[0]); bfr[1] = (short)f2bf(wlo[1]);
      bfr[2] = (short)f2bf(wlo[2]); bfr[3] = (short)f2bf(wlo[3]);
      bfr[4] = (short)f2bf(whi[0]); bfr[5] = (short)f2bf(whi[1]);
      bfr[6] = (short)f2bf(whi[2]); bfr[7] = (short)f2bf(whi[3]);
      C0 = __builtin_amdgcn_mfma_f32_16x16x32_bf16(xa0[ks], bfr, C0, 0, 0, 0);
      C1 = __builtin_amdgcn_mfma_f32_16x16x32_bf16(xa1[ks], bfr, C1, 0, 0, 0);
    }
    __builtin_amdgcn_sched_barrier(0);
    __builtin_amdgcn_s_barrier();          // readers done before buf overwrite
    __builtin_amdgcn_sched_barrier(0);
  }
  float* Red = &Ws[0][0];
#pragma unroll
  for (int i = 0; i < 4; ++i) {
    Red[w_id * 512 + (quad * 4 + i) * 16 + l15] = C0[i];
    Red[w_id * 512 + 256 + (quad * 4 + i) * 16 + l15] = C1[i];
  }
  __syncthreads();
  float* dst = khalf ? outB : outA;
#pragma unroll
  for (int e = t; e < 512; e += 256) {
    float s = Red[e] + Red[512 + e] + Red[1024 + e] + Red[1536 + e];
    int m = e >> 4, n = e & 15;
    if (khalf == 0 && bias) s += bias[row0 + n];
    dst[(size_t)m * Ntot + n0 + n] = s;
  }
}

// ---------------------------------------------------------------------------
// out = A + B (float4 groups), for split-K combine of the output projection.
// ---------------------------------------------------------------------------
__global__ __launch_bounds__(256) void k_add(
    const float* __restrict__ A, const float* __restrict__ B,
    float* __restrict__ o, int n4)
{
  int i = blockIdx.x * 256 + threadIdx.x;
  if (i < n4) {
    float4 a = ((const float4*)A)[i], b = ((const float4*)B)[i];
    float4 r; r.x = a.x + b.x; r.y = a.y + b.y; r.z = a.z + b.z; r.w = a.w + b.w;
    ((float4*)o)[i] = r;
  }
}

// ---------------------------------------------------------------------------
// RoPE: rq (3 variants: pos 12304+q / 4112+q / 2048+q, scale folded),
// RoPE'd k_new and v_new, all bf16. qkv = qkvA + qkvB (split-K halves).
// ---------------------------------------------------------------------------
__global__ __launch_bounds__(256) void k_rope(
    const float* __restrict__ qA, const float* __restrict__ qB,
    const float* __restrict__ cosn, const float* __restrict__ sinn,
    unsigned short* __restrict__ rq, unsigned short* __restrict__ knew,
    unsigned short* __restrict__ vnew)
{
  const int g = blockIdx.x * 256 + threadIdx.x;
  const float LOGTH = 9.210340371976184f; // ln(10000)
  if (g < 393216) {                          // rq: [var][w][head][q][d]
    int d = g & 127, q = (g >> 7) & 15, head = (g >> 11) & 31, w = (g >> 16) & 1, var = g >> 17;
    int tok = w * 16 + q;
    int col = head * 128 + d;
    size_t ix = (size_t)tok * 6144 + col;
    float val = qA[ix] + qB[ix];
    size_t ir = (d < 64) ? ix + 64 : ix - 64;
    float rot = qA[ir] + qB[ir];
    if (d < 64) rot = -rot;
    int pos = (var == 0 ? 12304 : (var == 1 ? 4112 : 2048)) + q;
    int i = d & 63;
    float inv = expf(-(float)i * (LOGTH / 64.0f));
    float ang = (float)pos * inv;
    float c = cosf(ang), s = sinf(ang);
    rq[g] = f2bf((val * c + rot * s) * SCALE);
  } else {
    int g2 = g - 393216;
    if (g2 < 65536) {
      int isv = (g2 >= 32768);
      if (isv) g2 -= 32768;
      int d = g2 & 127, q = (g2 >> 7) & 15, h = (g2 >> 11) & 7, w = (g2 >> 14) & 1;
      int tok = w * 16 + q;
      if (isv) {
        size_t ix = (size_t)tok * 6144 + 5120 + h * 128 + d;
        vnew[g2] = f2bf(qA[ix] + qB[ix]);
      } else {
        size_t ix = (size_t)tok * 6144 + 4096 + h * 128 + d;
        float val = qA[ix] + qB[ix];
        size_t ir = (d < 64) ? ix + 64 : ix - 64;
        float rot = qA[ir] + qB[ir];
        if (d < 64) rot = -rot;
        float c = cosn[tok * 128 + d], s = sinn[tok * 128 + d];
        knew[g2] = f2bf(val * c + rot * s);
      }
    }
  }
}

// ---------------------------------------------------------------------------
// Flash-attention partials, fixed-max softmax, SWAPPED QK operands.
// R2: asm-load prefetch + double-buffered LDS + ONE raw s_barrier per tile
// (no __syncthreads => no vmcnt(0) drains at barriers; prefetch stays in
// flight across the barrier; the per-tile drain happens a full compute
// phase after issue, so it is ~free in steady state).
// Single-barrier safety: per-wave order is  drain -> write buf[st&1] ->
// issue(st+1) -> lgkmcnt(0) -> barrier -> compute buf[st&1].  A wave doing
// write(st+1) has passed barrier(st), which implies all waves finished
// compute(st-1) (program order: compute(st-1) < write(st) < barrier(st)),
// so overwriting buf[(st+1)&1] == buf[(st-1)&1] is race-free.
// ---------------------------------------------------------------------------
__global__ __launch_bounds__(512, 2) void k_attn(
    const float* __restrict__ shk, const float* __restrict__ shv,
    const float* __restrict__ w0k, const float* __restrict__ w0v,
    const float* __restrict__ w1k, const float* __restrict__ w1v,
    const unsigned short* __restrict__ rq,
    const unsigned short* __restrict__ knew, const unsigned short* __restrict__ vnew,
    __half* __restrict__ accP, float* __restrict__ lP)
{
  __shared__ alignas(16) unsigned short Ks[2][64 * 136];    // [key][d] bf16
  __shared__ alignas(16) unsigned short Vts[2][128 * 72];   // [d][key] bf16
#ifndef HAVE_MFMA16
  __shared__ alignas(16) unsigned short Plds[8 * 16 * 72];
#endif

  const int h = blockIdx.x / 50;
  const int cidx = blockIdx.x % 50;
  int kind, k0, nk; bool is_new;
  if (cidx < 32)      { kind = 0; k0 = cidx * 256; nk = 256; is_new = false; }
  else if (cidx < 41) { int c = cidx - 32; kind = 1; k0 = c * 256; nk = (c == 8) ? 16 : 256; is_new = (c == 8); }
  else                { int c = cidx - 41; kind = 2; k0 = c * 256; nk = (c == 8) ? 16 : 256; is_new = (c == 8); }

  const int t = threadIdx.x;
  const int w_id = t >> 6;        // 0..7
  const int lane = t & 63;
  const int l15 = lane & 15;
  const int quad = lane >> 4;
  const int worker = w_id >> 2;   // 0..1
  const int hq = w_id & 3;        // q-head within kv group
  // staging decompositions (512 threads)
  const int col4 = t & 31;        // K: float4 column within row
  const int rowb = t >> 5;        // K: base row 0..15
  const int dv = t & 127;         // V: d column
  const int tg = t >> 7;          // V: key-row group 0..3

  int var; bool causal;
  if (kind == 0)      { var = 0; causal = false; }
  else if (kind == 1) { var = (worker == 0) ? 2 : 1; causal = (worker == 0); }
  else                { var = (worker == 1) ? 2 : 1; causal = (worker == 1); }

  const float* Ksrc = (kind == 0) ? (shk + (size_t)h * LSH * 128)
                     : (kind == 1) ? (w0k + (size_t)h * LWK * 128)
                                   : (w1k + (size_t)h * LWK * 128);
  const float* Vsrc = (kind == 0) ? (shv + (size_t)h * LSH * 128)
                     : (kind == 1) ? (w0v + (size_t)h * LWK * 128)
                                   : (w1v + (size_t)h * LWK * 128);
  const int wseg = (kind == 2) ? 1 : 0;
  const unsigned short* knsrc = knew + ((size_t)wseg * 8 + h) * 16 * 128;
  const unsigned short* vnsrc = vnew + ((size_t)wseg * 8 + h) * 16 * 128;

  // B-fragment of rq for this wave's head (B[n=q][k=d])
  const int head = h * 4 + hq;
  short8 arq[4];
  {
    const unsigned short* base =
        rq + ((((size_t)var * 2 + worker) * 32 + head) * 16 + l15) * 128 + quad * 8;
#pragma unroll
    for (int ks = 0; ks < 4; ++ks) arq[ks] = *(const short8*)(base + ks * 32);
  }

  float lrow = 0.f;
  f32x4 acc[8];
#pragma unroll
  for (int dt = 0; dt < 8; ++dt) acc[dt] = {0.f,0.f,0.f,0.f};

  // raw fp32 staging registers (asm-defined -> cannot be sunk/drained)
  float4 kf[4];
  float  vf[16];

  const float* kbase = Ksrc + (size_t)(k0 + rowb) * 128 + col4 * 4;
  const float* vbase = Vsrc + (size_t)(k0 + tg * 8) * 128 + dv;

  auto issue_tile = [&](int st) {
    const float* kp = kbase + (size_t)st * 64 * 128;
#pragma unroll
    for (int i = 0; i < 4; ++i) gload_f4(kf[i], kp + (size_t)i * 16 * 128);
    const float* vp = vbase + (size_t)st * 64 * 128;
#pragma unroll
    for (int g = 0; g < 2; ++g)
#pragma unroll
      for (int i = 0; i < 8; ++i)
        gload_f1(vf[g * 8 + i], vp + (size_t)(g * 32 + i) * 128);
  };

  const int nst = (nk + 63) >> 6;
  if (!is_new) {
    issue_tile(0);
  } else {
    // 16 new tokens, bf16 source (plain loads; nst==1 so no pipelining).
    // Clamp rows (&15); garbage rows are killed by the score mask.
#pragma unroll
    for (int i = 0; i < 4; ++i) {
      ushort4 p = *(const ushort4*)(knsrc + (size_t)((i * 16 + rowb) & 15) * 128 + col4 * 4);
      kf[i].x = bf2f(p.x); kf[i].y = bf2f(p.y);
      kf[i].z = bf2f(p.z); kf[i].w = bf2f(p.w);
    }
#pragma unroll
    for (int g = 0; g < 2; ++g)
#pragma unroll
      for (int i = 0; i < 8; ++i)
        vf[g * 8 + i] = bf2f(vnsrc[(size_t)((g * 32 + tg * 8 + i) & 15) * 128 + dv]);
  }

  for (int st = 0; st < nst; ++st) {
    const int pb = st & 1;
    // ---- drain MY prefetch (issued one full compute phase ago) ----
    asm volatile("s_waitcnt vmcnt(0)" ::: "memory");
    __builtin_amdgcn_sched_barrier(0);
    // ---- convert + regs -> LDS buf[pb] ----
#pragma unroll
    for (int i = 0; i < 4; ++i) {
      ushort4 p; p.x = f2bf(kf[i].x); p.y = f2bf(kf[i].y);
      p.z = f2bf(kf[i].z); p.w = f2bf(kf[i].w);
      *(ushort4*)(&Ks[pb][(i * 16 + rowb) * 136 + col4 * 4]) = p;
    }
#pragma unroll
    for (int g = 0; g < 2; ++g) {
      ushort8v p;
#pragma unroll
      for (int i = 0; i < 8; ++i) p[i] = f2bf(vf[g * 8 + i]);
      *(ushort8v*)(&Vts[pb][dv * 72 + (g * 4 + tg) * 8]) = p;
    }
    // ---- issue next tile's loads (stay in flight across the barrier) ----
    if (st + 1 < nst) issue_tile(st + 1);
    asm volatile("s_waitcnt lgkmcnt(0)" ::: "memory");  // my ds_writes visible
    __builtin_amdgcn_sched_barrier(0);
    __builtin_amdgcn_s_barrier();                        // raw: NO vmcnt drain
    __builtin_amdgcn_sched_barrier(0);

    // ---- S' = K x Q^T : A = K-frag (m=key), B = rq (n=q) ----
    f32x4 S[4];
#pragma unroll
    for (int nt = 0; nt < 4; ++nt) S[nt] = {0.f,0.f,0.f,0.f};
#pragma unroll
    for (int ks = 0; ks < 4; ++ks)
#pragma unroll
      for (int nt = 0; nt < 4; ++nt) {
        short8 kfr = *(const short8*)(&Ks[pb][(nt * 16 + l15) * 136 + ks * 32 + quad * 8]);
        S[nt] = __builtin_amdgcn_mfma_f32_16x16x32_bf16(kfr, arq[ks], S[nt], 0, 0, 0);
      }
    if (is_new) {
#pragma unroll
      for (int nt = 0; nt < 4; ++nt)
#pragma unroll
        for (int i = 0; i < 4; ++i) {
          int loc = st * 64 + nt * 16 + quad * 4 + i;   // key index
          if (loc >= nk || (causal && loc > l15)) S[nt][i] = -3.0e38f;
        }
    }
    float rs = 0.0f;
#pragma unroll
    for (int nt = 0; nt < 4; ++nt)
#pragma unroll
      for (int i = 0; i < 4; ++i) {
        float p = __expf(fminf(S[nt][i], 60.0f));
        S[nt][i] = p;
        rs += p;
      }
#ifdef HAVE_MFMA16
    short4v pv[4];
#pragma unroll
    for (int nt = 0; nt < 4; ++nt) {
      short4v pp;
      pp[0] = (short)f2bf(S[nt][0]); pp[1] = (short)f2bf(S[nt][1]);
      pp[2] = (short)f2bf(S[nt][2]); pp[3] = (short)f2bf(S[nt][3]);
      pv[nt] = pp;
    }
#else
#pragma unroll
    for (int nt = 0; nt < 4; ++nt)
#pragma unroll
      for (int i = 0; i < 4; ++i)
        Plds[w_id * (16 * 72) + l15 * 72 + nt * 16 + quad * 4 + i] = f2bf(S[nt][i]);
#endif
    // denominator: sum across quads (keys); q = l15 fixed per lane
    rs += __shfl_xor(rs, 16, 64);
    rs += __shfl_xor(rs, 32, 64);
    lrow += rs;

    // ---- PV ----
#ifdef HAVE_MFMA16
#pragma unroll
    for (int dt = 0; dt < 8; ++dt)
#pragma unroll
      for (int kc = 0; kc < 4; ++kc) {
        short4v vfr = *(const short4v*)(&Vts[pb][(dt * 16 + l15) * 72 + kc * 16 + quad * 4]);
        acc[dt] = __builtin_amdgcn_mfma_f32_16x16x16bf16_1k(pv[kc], vfr, acc[dt], 0, 0, 0);
      }
#else
    short8 ap[2];
#pragma unroll
    for (int ks2 = 0; ks2 < 2; ++ks2)
      ap[ks2] = *(const short8*)(
          &Plds[w_id * (16 * 72) + l15 * 72 + ks2 * 32 + quad * 8]);
#pragma unroll
    for (int dt = 0; dt < 8; ++dt)
#pragma unroll
      for (int ks2 = 0; ks2 < 2; ++ks2) {
        short8 vfr = *(const short8*)(&Vts[pb][(dt * 16 + l15) * 72 + ks2 * 32 + quad * 8]);
        acc[dt] = __builtin_amdgcn_mfma_f32_16x16x32_bf16(ap[ks2], vfr, acc[dt], 0, 0, 0);
      }
#endif
  }

  // ---- write partials (acc layout: row = q = quad*4+i, col = d = dt*16+l15)
  __half* accB = accP + (size_t)blockIdx.x * 128 * 128;
  const int wrow = worker * 64 + hq * 16;
#pragma unroll
  for (int dt = 0; dt < 8; ++dt)
#pragma unroll
    for (int i = 0; i < 4; ++i) {
      int row = wrow + quad * 4 + i;
      int d = dt * 16 + l15;
      accB[row * 128 + d] = __float2half(acc[dt][i]);
    }
  if (quad == 0) {
    int row = wrow + l15;    // q = l15
    lP[(size_t)blockIdx.x * 128 + row] = lrow;
  }
}

// ---------------------------------------------------------------------------
// Combine 50 chunk-partials per (head,row): plain sums (fixed-max softmax).
// ---------------------------------------------------------------------------
__global__ __launch_bounds__(128) void k_combine(
    const __half* __restrict__ accP, const float* __restrict__ lP,
    unsigned short* __restrict__ attnX)
{
  __shared__ float sl[50];
  const int h = blockIdx.x >> 7;
  const int r = blockIdx.x & 127;
  const int d = threadIdx.x;
  if (d < 50) sl[d] = lP[(size_t)(h * 50 + d) * 128 + r];
  __syncthreads();
  float L = 0.0f, A = 0.0f;
#pragma unroll
  for (int c = 0; c < 50; ++c) L += sl[c];
#pragma unroll
  for (int cc = 0; cc < 50; cc += 10) {
    float p[10];
#pragma unroll
    for (int i = 0; i < 10; ++i)
      p[i] = __half2float(accP[((size_t)(h * 50 + cc + i) * 128 + r) * 128 + d]);
#pragma unroll
    for (int i = 0; i < 10; ++i) A += p[i];
  }
  int workerv = r >> 6, headpairv = (r >> 5) & 1, mtv = (r >> 4) & 1, q = r & 15;
  int head = h * 4 + headpairv * 2 + mtv;
  attnX[(size_t)(workerv * 16 + q) * 4096 + head * 128 + d] = f2bf(A / L);
}

// ---------------------------------------------------------------------------
extern "C" void kernel_launch(void* const* d_in, const int* in_sizes, int n_in,
                              void* d_out, int out_size, void* d_ws, size_t ws_size,
                              hipStream_t stream)
{
  const float* hs   = (const float*)d_in[0];
  const float* Wq   = (const float*)d_in[1];
  const float* bq   = (const float*)d_in[2];
  const float* Wk   = (const float*)d_in[3];
  const float* bk   = (const float*)d_in[4];
  const float* Wv   = (const float*)d_in[5];
  const float* bv   = (const float*)d_in[6];
  const float* Wo   = (const float*)d_in[7];
  const float* shk  = (const float*)d_in[8];
  const float* shv  = (const float*)d_in[9];
  const float* w0k  = (const float*)d_in[10];
  const float* w0v  = (const float*)d_in[11];
  const float* w1k  = (const float*)d_in[12];
  const float* w1v  = (const float*)d_in[13];
  const float* cosn = (const float*)d_in[14];
  const float* sinn = (const float*)d_in[15];
  float* out = (float*)d_out;

  char* ws = (char*)d_ws;
  float*          qkvA   = (float*)(ws + 0);                //  32*6144 f32
  unsigned short* rq     = (unsigned short*)(ws + 786432);  //  3*2*32*16*128 bf16
  unsigned short* knew   = (unsigned short*)(ws + 1572864); //  2*8*16*128 bf16
  unsigned short* vnew   = (unsigned short*)(ws + 1638400);
  unsigned short* hsbf   = (unsigned short*)(ws + 1703936); //  32*4096 bf16
  unsigned short* attnXb = (unsigned short*)(ws + 1966080); //  32*4096 bf16
  float*          lP     = (float*)(ws + 2228224);          //  400*128 f32
  __half*         accP   = (__half*)(ws + 2433024);         //  400*128*128 f16 (13.1 MB)
  float*          qkvB   = (float*)(ws + 15540224);         //  32*6144 f32
  // out-proj split-K halves live inside accP's region (accP consumed by then)
  float*          outA   = (float*)(ws + 2433024);
  float*          outB   = (float*)(ws + 2433024 + 786432);

  // 1. cast hidden_states to bf16
  k_cast<<<128, 256, 0, stream>>>(hs, hsbf, 32768);
  // 2. QKV projection, split-K x2 (bias in khalf==0 partial)
  k_gemm4<<<768, 256, 0, stream>>>(hsbf, Wq, Wk, Wv, bq, bk, bv, qkvA, qkvB, 6144);
  // 3. RoPE (q x 3 variants + k_new) + v_new, bf16 (sums qkvA+qkvB)
  k_rope<<<1792, 256, 0, stream>>>(qkvA, qkvB, cosn, sinn, rq, knew, vnew);
  // 4. flash-attention partials over 8 heads x 50 key-chunks (8 waves/block)
  k_attn<<<400, 512, 0, stream>>>(shk, shv, w0k, w0v, w1k, w1v, rq, knew, vnew, accP, lP);
  // 5. combine partials -> attnX (bf16)
  k_combine<<<1024, 128, 0, stream>>>(accP, lP, attnXb);
  // 6. output projection, split-K x2
  k_gemm4<<<512, 256, 0, stream>>>(attnXb, Wo, Wo, Wo, nullptr, nullptr, nullptr, outA, outB, 4096);
  // 7. sum halves -> d_out
  k_add<<<192, 256, 0, stream>>>(outA, outB, out, 49152);
}